// Round 6
// baseline (166.412 us; speedup 1.0000x reference)
//
#include <hip/hip_runtime.h>

#define NUM_USER   4096
#define NUM_ITEM   16384
#define NUM_HIDDEN 64
#define B_SZ       1024
#define L_SZ       50
#define NPAIR      (B_SZ * L_SZ)              // 51200
#define SEG_ITEMS  1024                       // cells per segment-strip
#define SEGS_PER_USER (NUM_ITEM / SEG_ITEMS)  // 16
#define NSEG       (NUM_USER * SEGS_PER_USER) // 65536
#define CAP        64                         // bin capacity (realistic max ~30)
#define NBUCKET    1024                       // bucketed unique-cell counters
#define FILL_BLOCKS 2048                      // fat blocks: 8/CU, 256 KB stores each
#define SEGS_PER_BLOCK (NSEG / FILL_BLOCKS)   // 32

// Thread-per-pair: serial 64-element dot (embeds are L2/L3-resident), then bin
// (key,val,rating) into the owning segment. key = (seq<<10)|item_low; max key
// == numpy C-order last write -> winner selection is order-independent.
__global__ void pair_bin_kernel(const int* __restrict__ idx_user,
                                const int* __restrict__ item_sets,
                                const float* __restrict__ rating_sets,
                                const float* __restrict__ embed_user,
                                const float* __restrict__ embed_item,
                                unsigned int* __restrict__ seg_count,
                                unsigned int* __restrict__ seg_key,
                                float* __restrict__ seg_val,
                                float* __restrict__ seg_rat) {
    const int p  = blockIdx.x * 256 + threadIdx.x;   // 200 blocks x 256 = 51200 exactly
    const int b  = p / L_SZ;
    const int u  = idx_user[b];
    const int it = item_sets[p];

    const float4* eu = (const float4*)(embed_user + (size_t)u  * NUM_HIDDEN);
    const float4* ei = (const float4*)(embed_item + (size_t)it * NUM_HIDDEN);
    float acc = 0.f;
    #pragma unroll 4
    for (int j = 0; j < NUM_HIDDEN / 4; ++j) {
        float4 a = eu[j], c = ei[j];
        acc += a.x * c.x + a.y * c.y + a.z * c.z + a.w * c.w;
    }

    const int seg = (u << 4) | (it >> 10);
    unsigned int slot = atomicAdd(&seg_count[seg], 1u);
    if (slot < CAP) {
        const int base = seg * CAP + (int)slot;
        seg_key[base] = ((unsigned int)p << 10) | (unsigned int)(it & (SEG_ITEMS - 1));
        seg_val[base] = acc;
        seg_rat[base] = rating_sets[p];
    }
}

// Fat fill+inject: each block streams 32 consecutive segment-strips (256 KB of
// stores, memset-shaped). Empty strip (common) -> pure float4 zero stores.
// Non-empty -> scan the k (~4) binned entries with static-index selection,
// resolve last-write-wins by max key, count unique cells for sparsity.
__global__ void fill_inject_kernel(const unsigned int* __restrict__ seg_count,
                                   const unsigned int* __restrict__ seg_key,
                                   const float* __restrict__ seg_val,
                                   const float* __restrict__ seg_rat,
                                   float4* __restrict__ pred4,
                                   float4* __restrict__ label4,
                                   unsigned int* __restrict__ ucount) {
    const int t    = threadIdx.x;                     // 0..255
    const int seg0 = blockIdx.x * SEGS_PER_BLOCK;
    const int j0   = t * 4;                           // thread's first item within a strip
    unsigned int nmatch = 0;

    for (int s = 0; s < SEGS_PER_BLOCK; ++s) {
        const int seg = seg0 + s;
        float4 pv = {0.f, 0.f, 0.f, 0.f};
        float4 lv = {0.f, 0.f, 0.f, 0.f};

        unsigned int k = seg_count[seg];              // block-uniform load
        if (k) {                                      // block-uniform branch
            if (k > CAP) k = CAP;
            int bk0 = -1, bk1 = -1, bk2 = -1, bk3 = -1;
            int bi0 = 0,  bi1 = 0,  bi2 = 0,  bi3 = 0;
            const int base = seg * CAP;
            for (int i = 0; i < (int)k; ++i) {
                const int key = (int)seg_key[base + i];        // < 2^26, sign-safe
                const int rel = (key & (SEG_ITEMS - 1)) - j0;
                bool m0 = (rel == 0) && (key > bk0); bk0 = m0 ? key : bk0; bi0 = m0 ? i : bi0;
                bool m1 = (rel == 1) && (key > bk1); bk1 = m1 ? key : bk1; bi1 = m1 ? i : bi1;
                bool m2 = (rel == 2) && (key > bk2); bk2 = m2 ? key : bk2; bi2 = m2 ? i : bi2;
                bool m3 = (rel == 3) && (key > bk3); bk3 = m3 ? key : bk3; bi3 = m3 ? i : bi3;
            }
            if (bk0 >= 0) { pv.x = seg_val[base + bi0]; lv.x = seg_rat[base + bi0]; ++nmatch; }
            if (bk1 >= 0) { pv.y = seg_val[base + bi1]; lv.y = seg_rat[base + bi1]; ++nmatch; }
            if (bk2 >= 0) { pv.z = seg_val[base + bi2]; lv.z = seg_rat[base + bi2]; ++nmatch; }
            if (bk3 >= 0) { pv.w = seg_val[base + bi3]; lv.w = seg_rat[base + bi3]; ++nmatch; }
        }

        const size_t pos = (size_t)seg * (SEG_ITEMS / 4) + t; // float4 index, coalesced
        pred4[pos]  = pv;
        label4[pos] = lv;
    }

    // unique-cell contribution for the sparsity scalar (bucketed: no contention)
    #pragma unroll
    for (int m = 32; m >= 1; m >>= 1) nmatch += __shfl_xor(nmatch, m, 64);
    if ((t & 63) == 0 && nmatch)
        atomicAdd(&ucount[blockIdx.x & (NBUCKET - 1)], nmatch);
}

// One block: reduce the NBUCKET partial counts, emit sparsity scalar.
__global__ void sparsity_kernel(const unsigned int* __restrict__ ucount,
                                float* __restrict__ out) {
    __shared__ unsigned int warp_sum[4];
    const int t = threadIdx.x;            // 256 threads = 4 waves
    unsigned int s = 0;
    #pragma unroll
    for (int i = 0; i < NBUCKET / 256; ++i) s += ucount[t + i * 256];
    #pragma unroll
    for (int m = 32; m >= 1; m >>= 1) s += __shfl_xor(s, m, 64);
    if ((t & 63) == 0) warp_sum[t >> 6] = s;
    __syncthreads();
    if (t == 0) {
        unsigned int total = warp_sum[0] + warp_sum[1] + warp_sum[2] + warp_sum[3];
        out[0] = (float)((double)NUM_USER * (double)NUM_ITEM / (double)total);
    }
}

extern "C" void kernel_launch(void* const* d_in, const int* in_sizes, int n_in,
                              void* d_out, int out_size, void* d_ws, size_t ws_size,
                              hipStream_t stream) {
    const int*   idx_user    = (const int*)d_in[0];
    const int*   item_sets   = (const int*)d_in[1];
    const float* rating_sets = (const float*)d_in[2];
    const float* embed_user  = (const float*)d_in[3];
    const float* embed_item  = (const float*)d_in[4];

    float* pred_mask = (float*)d_out;
    float* label     = pred_mask + (size_t)NUM_USER * NUM_ITEM;
    float* sparsity  = label     + (size_t)NUM_USER * NUM_ITEM;

    // ws layout: [seg_count: NSEG u32][ucount: NBUCKET u32][key|val|rat: NSEG*CAP each]
    unsigned int* seg_count = (unsigned int*)d_ws;
    unsigned int* ucount    = seg_count + NSEG;
    unsigned int* seg_key   = ucount + NBUCKET;
    float*        seg_val   = (float*)(seg_key + (size_t)NSEG * CAP);
    float*        seg_rat   = seg_val + (size_t)NSEG * CAP;

    // Zero only the counters (264 KB); bin payload slots 0..count-1 are always
    // freshly stored before being read.
    hipMemsetAsync(d_ws, 0, (size_t)(NSEG + NBUCKET) * sizeof(int), stream);

    pair_bin_kernel<<<NPAIR / 256, 256, 0, stream>>>(idx_user, item_sets, rating_sets,
                                                     embed_user, embed_item,
                                                     seg_count, seg_key, seg_val, seg_rat);
    fill_inject_kernel<<<FILL_BLOCKS, 256, 0, stream>>>(seg_count, seg_key, seg_val, seg_rat,
                                                        (float4*)pred_mask, (float4*)label,
                                                        ucount);
    sparsity_kernel<<<1, 256, 0, stream>>>(ucount, sparsity);
}